// Round 4
// baseline (834.592 us; speedup 1.0000x reference)
//
#include <hip/hip_runtime.h>
#include <cstdint>
#include <cstddef>

#define NN 50000
#define EE 800000
#define EP 850000   // EE + NN self-loops
#define DD 128
#define BB 1024
#define D3 384
#define NTL2 391    // ceil(NN/128) column tiles of lin2
#define NEG_SLOPE 0.2f

typedef __attribute__((ext_vector_type(8))) short short8;
typedef __attribute__((ext_vector_type(4))) float f32x4;
typedef unsigned short u16;
typedef unsigned int u32;

__device__ __forceinline__ u16 f2bf(float f) {
  u32 u = __float_as_uint(f);
  u += 0x7fffu + ((u >> 16) & 1u);
  return (u16)(u >> 16);
}
__device__ __forceinline__ float bflo(u32 u) { return __uint_as_float(u << 16); }
__device__ __forceinline__ float bfhi(u32 u) { return __uint_as_float(u & 0xffff0000u); }

// async global->LDS 16B: per-lane global addr, wave-uniform LDS base (+lane*16 by HW)
__device__ __forceinline__ void gl2lds16(const u16* g, u16* lds_base_uniform) {
  __builtin_amdgcn_global_load_lds((const __attribute__((address_space(1))) u32*)g,
                                   (__attribute__((address_space(3))) u32*)lds_base_uniform,
                                   16, 0, 0);
}

// ---------------- fused fp32 -> bf16 converts (5 regions, 1 launch) ----------------
__global__ void k_f2bf5(const float* __restrict__ s0, u16* __restrict__ d0, int n0,
                        const float* __restrict__ s1, u16* __restrict__ d1, int n1,
                        const float* __restrict__ s2, u16* __restrict__ d2, int n2,
                        const float* __restrict__ s3, u16* __restrict__ d3, int n3,
                        const float* __restrict__ s4, u16* __restrict__ d4, int n4) {
  int i = blockIdx.x * 256 + threadIdx.x;
  const float* s; u16* d; int j;
  int c0 = n0, c1 = c0 + n1, c2 = c1 + n2, c3 = c2 + n3, c4 = c3 + n4;
  if      (i < c0) { s = s0; d = d0; j = i; }
  else if (i < c1) { s = s1; d = d1; j = i - c0; }
  else if (i < c2) { s = s2; d = d2; j = i - c1; }
  else if (i < c3) { s = s3; d = d3; j = i - c2; }
  else if (i < c4) { s = s4; d = d4; j = i - c3; }
  else return;
  float4 v = ((const float4*)s)[j];
  ushort4 o;
  o.x = f2bf(v.x); o.y = f2bf(v.y); o.z = f2bf(v.z); o.w = f2bf(v.w);
  ((ushort4*)d)[j] = o;
}

// ---------------- CSR build (counting sort by dst) ----------------
__global__ void k_count(const int* __restrict__ eidx, int* __restrict__ cnt) {
  int e = blockIdx.x * 256 + threadIdx.x;
  if (e >= EP) return;
  int d = (e < EE) ? eidx[EE + e] : (e - EE);
  atomicAdd(&cnt[d], 1);
}

// shfl-based block scan: 16 waves x 64-lane shfl scan, 2 barriers total
__global__ void k_scan1(const int* __restrict__ cnt, int* __restrict__ offs, int* __restrict__ bsum) {
  __shared__ int wsum[16], wexc[16];
  int tid = threadIdx.x;
  int wv = tid >> 6, lane = tid & 63;
  int i = blockIdx.x * 1024 + tid;
  int v = (i < NN) ? cnt[i] : 0;
  int s = v;
  #pragma unroll
  for (int off = 1; off < 64; off <<= 1) {
    int t = __shfl_up(s, off, 64);
    if (lane >= off) s += t;
  }
  if (lane == 63) wsum[wv] = s;
  __syncthreads();
  if (tid < 16) {
    int u = wsum[tid];
    int e = u;
    #pragma unroll
    for (int off = 1; off < 16; off <<= 1) {
      int t = __shfl_up(e, off, 64);
      if (tid >= off) e += t;
    }
    wexc[tid] = e - u;   // exclusive wave offset
  }
  __syncthreads();
  int inc = s + wexc[wv];
  if (i < NN) offs[i] = inc - v;   // exclusive
  if (tid == 1023) bsum[blockIdx.x] = inc;
}

// scan of 49 block sums (done redundantly per block, wave 0) + apply, fused
__global__ void k_scan23(int* __restrict__ offs, const int* __restrict__ bsum, int* __restrict__ cur) {
  __shared__ int bso_s[64];
  int tid = threadIdx.x;
  if (tid < 64) {
    int v = (tid < 49) ? bsum[tid] : 0;
    int s = v;
    #pragma unroll
    for (int off = 1; off < 64; off <<= 1) {
      int t = __shfl_up(s, off, 64);
      if (tid >= off) s += t;
    }
    bso_s[tid] = s - v;
  }
  __syncthreads();
  int i = blockIdx.x * 256 + tid;
  if (i >= NN) return;
  int o = offs[i] + bso_s[i >> 10];
  offs[i] = o;
  cur[i] = o;
}

__global__ void k_scatter(const int* __restrict__ eidx, int* __restrict__ cur, int* __restrict__ ssrc) {
  int e = blockIdx.x * 256 + threadIdx.x;
  if (e >= EP) return;
  int s, d;
  if (e < EE) { s = eidx[e]; d = eidx[EE + e]; } else { s = e - EE; d = s; }
  int p = atomicAdd(&cur[d], 1);
  ssrc[p] = s;
}

// ---------------- m97-style tiled MFMA GEMM (128x128 tile) ----------------
// C[M,N] = A[M,K] @ B[N,K]^T (+bias). A,B bf16 via global_load_lds.
// ATT   : epilogue computes as_ = h@attS, ad_ = h@attD per row -> pm/ps (gridDim.x==1, N==128).
// GATHER: A row r is xmap-indirected: A[xmap[r*3 + kt/128]*DD + (kt&127)+...] (lin1 concat-gather).
template<bool OUT_BF16, bool ATT, bool GATHER>
__global__ __launch_bounds__(256) void gemm_tile(const u16* __restrict__ A, const u16* __restrict__ B,
                                                 const float* __restrict__ bias, void* __restrict__ Cv,
                                                 int M, int N, int K,
                                                 float* __restrict__ pm, float* __restrict__ ps,
                                                 const float* __restrict__ attS, const float* __restrict__ attD,
                                                 const int* __restrict__ xmap) {
  __shared__ u16 As[16 * 512];   // 16 KB: [128 rows][64 k] bf16, swizzled
  __shared__ u16 Bs[16 * 512];
  int tid = threadIdx.x;
  int w = tid >> 6, lane = tid & 63;
  int l15 = lane & 15, q = lane >> 4;

  int bx = blockIdx.x, by = blockIdx.y;
  int n0 = bx * 128, m0 = by * 128;
  int mh = w & 1, nh = w >> 1;

  // staging lane geometry
  int lr = lane >> 3;                 // row-in-8
  int cg = (lane & 7) ^ lr;           // global chunk to fetch for this lane's slot

  f32x4 acc[4][4] = {};

  for (int kt = 0; kt < K; kt += 64) {
    // ---- stage A ----
    #pragma unroll
    for (int i = 0; i < 4; i++) {
      int inst = (w << 2) | i;
      int row = inst * 8 + lr;
      int grow = m0 + row; if (grow > M - 1) grow = M - 1;
      const u16* src;
      if constexpr (GATHER) {
        int node = xmap[grow * 3 + (kt >> 7)];
        src = A + (size_t)node * DD + (kt & 127) + cg * 8;
      } else {
        src = A + (size_t)grow * K + kt + cg * 8;
      }
      gl2lds16(src, &As[inst * 512]);
    }
    // ---- stage B ----
    #pragma unroll
    for (int i = 0; i < 4; i++) {
      int inst = (w << 2) | i;
      int row = inst * 8 + lr;
      int gn = n0 + row; if (gn > N - 1) gn = N - 1;
      gl2lds16(B + (size_t)gn * K + kt + cg * 8, &Bs[inst * 512]);
    }
    __builtin_amdgcn_s_waitcnt(0x0f70);  // vmcnt(0) for global_load_lds
    __syncthreads();

    // ---- compute: 2 kk-steps x 16 MFMA ----
    #pragma unroll
    for (int kk = 0; kk < 2; kk++) {
      short8 a[4], b[4];
      int cbase = kk * 4 + q;
      int csw = cbase ^ (l15 & 7);
      #pragma unroll
      for (int mi = 0; mi < 4; mi++) {
        int row = (mh * 4 + mi) * 16 + l15;
        a[mi] = *(const short8*)(&As[row * 64 + csw * 8]);
      }
      #pragma unroll
      for (int nt = 0; nt < 4; nt++) {
        int row = (nh * 4 + nt) * 16 + l15;
        b[nt] = *(const short8*)(&Bs[row * 64 + csw * 8]);
      }
      #pragma unroll
      for (int mi = 0; mi < 4; mi++)
        #pragma unroll
        for (int nt = 0; nt < 4; nt++)
          acc[mi][nt] = __builtin_amdgcn_mfma_f32_16x16x32_bf16(a[mi], b[nt], acc[mi][nt], 0, 0, 0);
    }
    __syncthreads();   // WAR before next stage; also frees LDS for epilogue reuse
  }

  // ---- epilogue ----
  float bsv[4], asv[4], adv[4];
  #pragma unroll
  for (int nt = 0; nt < 4; nt++) {
    int col = n0 + nh * 64 + nt * 16 + l15;
    bsv[nt] = (bias != nullptr && col < N) ? bias[col] : 0.0f;
    if constexpr (ATT) { asv[nt] = attS[col]; adv[nt] = attD[col]; }
  }
  float* sredS = (float*)As;   // ATT: s-partials
  float* sredD = (float*)Bs;   // ATT: d-partials

  #pragma unroll
  for (int mi = 0; mi < 4; mi++) {
    #pragma unroll
    for (int r = 0; r < 4; r++) {
      int rw = m0 + mh * 64 + mi * 16 + q * 4 + r;
      float v[4];
      #pragma unroll
      for (int nt = 0; nt < 4; nt++) {
        int col = n0 + nh * 64 + nt * 16 + l15;
        v[nt] = acc[mi][nt][r] + bsv[nt];
        if (col < N && rw < M) {
          if constexpr (OUT_BF16) ((u16*)Cv)[(size_t)rw * N + col] = f2bf(v[nt]);
          else                    ((float*)Cv)[(size_t)rw * N + col] = v[nt];
        }
      }
      if constexpr (ATT) {
        float psm = v[0] * asv[0] + v[1] * asv[1] + v[2] * asv[2] + v[3] * asv[3];
        float pdm = v[0] * adv[0] + v[1] * adv[1] + v[2] * adv[2] + v[3] * adv[3];
        #pragma unroll
        for (int o = 1; o <= 8; o <<= 1) { psm += __shfl_xor(psm, o, 64); pdm += __shfl_xor(pdm, o, 64); }
        if (l15 == 0) {
          int ri = w * 64 + mi * 16 + q * 4 + r;
          sredS[ri] = psm;
          sredD[ri] = pdm;
        }
      }
    }
  }
  if constexpr (ATT) {
    __syncthreads();
    int t = threadIdx.x;
    if (t < 128) {
      int half = t >> 6, rr = t & 63;
      int grow = m0 + half * 64 + rr;
      if (grow < M) {
        pm[grow] = sredS[half * 64 + rr] + sredS[half * 64 + 128 + rr];   // as_
        ps[grow] = sredD[half * 64 + rr] + sredD[half * 64 + 128 + rr];   // ad_
      }
    }
  }
}

// ---------------- lin2 GEMM: 256(M)x128(N) tile, K=384, fused softmax partials ----------------
// A bf16 [1024][384], B bf16 [50000][384]. 4 waves; wave w owns rows [w*64, w*64+64) x all 128 cols.
// 256-row tile halves B re-streams (4 passes) and raises MFMA:staging 1.33x vs 128x128.
template<bool OUT_BF16>
__global__ __launch_bounds__(256) void gemm_lin2(const u16* __restrict__ A, const u16* __restrict__ B,
                                                 const float* __restrict__ bias, void* __restrict__ Cv,
                                                 float* __restrict__ pm, float* __restrict__ ps) {
  const int M = BB, N = NN, K = D3;
  __shared__ u16 As[32 * 512];   // 32 KB: 256 rows x 64 k, swizzled
  __shared__ u16 Bs[16 * 512];   // 16 KB: 128 rows x 64 k
  int tid = threadIdx.x;
  int w = tid >> 6, lane = tid & 63;
  int l15 = lane & 15, q = lane >> 4;

  // bijective XCD-chunked swizzle (nwg = 391*4 = 1564, not /8): m204 formula.
  int nwg = gridDim.x * gridDim.y;
  int id = blockIdx.y * gridDim.x + blockIdx.x;
  int qq = nwg >> 3, rr2 = nwg & 7;
  int xcd = id & 7, pos = id >> 3;
  int s = (xcd < rr2 ? xcd * (qq + 1) : rr2 * (qq + 1) + (xcd - rr2) * qq) + pos;
  int by = s & 3, bx = s >> 2;   // row-tiles fastest within an XCD chunk

  int n0 = bx * 128, m0 = by * 256;
  int lr = lane >> 3;
  int cg = (lane & 7) ^ lr;

  f32x4 acc[4][8] = {};

  for (int kt = 0; kt < K; kt += 64) {
    // ---- stage A: 256 rows (8 insts/thread-group) ----
    #pragma unroll
    for (int i = 0; i < 8; i++) {
      int inst = (w << 3) | i;
      int row = inst * 8 + lr;
      gl2lds16(A + (size_t)(m0 + row) * K + kt + cg * 8, &As[inst * 512]);
    }
    // ---- stage B: 128 rows ----
    #pragma unroll
    for (int i = 0; i < 4; i++) {
      int inst = (w << 2) | i;
      int row = inst * 8 + lr;
      int gn = n0 + row; if (gn > N - 1) gn = N - 1;
      gl2lds16(B + (size_t)gn * K + kt + cg * 8, &Bs[inst * 512]);
    }
    __builtin_amdgcn_s_waitcnt(0x0f70);  // vmcnt(0)
    __syncthreads();

    // ---- compute: 2 kk-steps x 32 MFMA/wave ----
    #pragma unroll
    for (int kk = 0; kk < 2; kk++) {
      int csw = (kk * 4 + q) ^ (l15 & 7);
      short8 a[4];
      #pragma unroll
      for (int mi = 0; mi < 4; mi++) {
        int row = w * 64 + mi * 16 + l15;
        a[mi] = *(const short8*)(&As[row * 64 + csw * 8]);
      }
      #pragma unroll
      for (int nh2 = 0; nh2 < 2; nh2++) {   // split b-frags to cap live VGPRs
        short8 b[4];
        #pragma unroll
        for (int nt = 0; nt < 4; nt++) {
          int row = (nh2 * 4 + nt) * 16 + l15;
          b[nt] = *(const short8*)(&Bs[row * 64 + csw * 8]);
        }
        #pragma unroll
        for (int mi = 0; mi < 4; mi++)
          #pragma unroll
          for (int nt = 0; nt < 4; nt++)
            acc[mi][nh2 * 4 + nt] =
                __builtin_amdgcn_mfma_f32_16x16x32_bf16(a[mi], b[nt], acc[mi][nh2 * 4 + nt], 0, 0, 0);
      }
    }
    __syncthreads();
  }

  // ---- epilogue: store + per-row softmax partials (wave owns full 128-col span) ----
  float bsv[8];
  #pragma unroll
  for (int nt = 0; nt < 8; nt++) {
    int col = n0 + nt * 16 + l15;
    bsv[nt] = (col < N) ? bias[col] : 0.0f;
  }
  #pragma unroll
  for (int mi = 0; mi < 4; mi++) {
    #pragma unroll
    for (int r = 0; r < 4; r++) {
      int rw = m0 + w * 64 + mi * 16 + q * 4 + r;   // always < M (grid exact)
      float v[8];
      #pragma unroll
      for (int nt = 0; nt < 8; nt++) {
        int col = n0 + nt * 16 + l15;
        v[nt] = acc[mi][nt][r] + bsv[nt];
        if (col < N) {
          if constexpr (OUT_BF16) ((u16*)Cv)[(size_t)rw * N + col] = f2bf(v[nt]);
          else                    ((float*)Cv)[(size_t)rw * N + col] = v[nt];
        } else v[nt] = -3.0e38f;
      }
      float mx = v[0];
      #pragma unroll
      for (int nt = 1; nt < 8; nt++) mx = fmaxf(mx, v[nt]);
      #pragma unroll
      for (int o = 1; o <= 8; o <<= 1) mx = fmaxf(mx, __shfl_xor(mx, o, 64));
      float sme = 0.0f;
      #pragma unroll
      for (int nt = 0; nt < 8; nt++) sme += __expf(v[nt] - mx);
      #pragma unroll
      for (int o = 1; o <= 8; o <<= 1) sme += __shfl_xor(sme, o, 64);
      if (l15 == 0) {
        pm[(size_t)bx * M + rw] = mx;
        ps[(size_t)bx * M + rw] = sme;
      }
    }
  }
}

// ---------------- GAT aggregation: one wave per dst node, SINGLE PASS, bf16 out ----------------
// Softmax is shift-invariant; |e| is small with these weight scales, so no max pass.
// den accumulates identically in every lane (w computed redundantly) -> no reduction.
__global__ void k_agg(const u16* __restrict__ hb, const float* __restrict__ as_, const float* __restrict__ ad_,
                      const int* __restrict__ offs, const int* __restrict__ cnt, const int* __restrict__ ssrc,
                      const float* __restrict__ bias, u32* __restrict__ outp) {
  int wid = (blockIdx.x * 256 + threadIdx.x) >> 6;
  int lane = threadIdx.x & 63;
  if (wid >= NN) return;
  int start = offs[wid], deg = cnt[wid];
  float add = ad_[wid];

  const u32* hp = (const u32*)hb;   // row stride 64 u32
  float a0 = 0.0f, a1 = 0.0f, den = 0.0f;
  int i = 0;
  for (; i + 4 <= deg; i += 4) {
    int s0 = ssrc[start + i + 0], s1 = ssrc[start + i + 1];
    int s2 = ssrc[start + i + 2], s3 = ssrc[start + i + 3];
    u32 u0 = hp[(size_t)s0 * 64 + lane];
    u32 u1 = hp[(size_t)s1 * 64 + lane];
    u32 u2 = hp[(size_t)s2 * 64 + lane];
    u32 u3 = hp[(size_t)s3 * 64 + lane];
    float e0 = as_[s0] + add, e1 = as_[s1] + add, e2 = as_[s2] + add, e3 = as_[s3] + add;
    e0 = (e0 >= 0.0f) ? e0 : NEG_SLOPE * e0;
    e1 = (e1 >= 0.0f) ? e1 : NEG_SLOPE * e1;
    e2 = (e2 >= 0.0f) ? e2 : NEG_SLOPE * e2;
    e3 = (e3 >= 0.0f) ? e3 : NEG_SLOPE * e3;
    float w0 = __expf(e0), w1 = __expf(e1), w2 = __expf(e2), w3 = __expf(e3);
    den += (w0 + w1) + (w2 + w3);
    a0 += w0 * bflo(u0) + w1 * bflo(u1) + w2 * bflo(u2) + w3 * bflo(u3);
    a1 += w0 * bfhi(u0) + w1 * bfhi(u1) + w2 * bfhi(u2) + w3 * bfhi(u3);
  }
  for (; i < deg; i++) {
    int s = ssrc[start + i];
    u32 u = hp[(size_t)s * 64 + lane];
    float e = as_[s] + add;
    e = (e >= 0.0f) ? e : NEG_SLOPE * e;
    float wg = __expf(e);
    den += wg;
    a0 += wg * bflo(u);
    a1 += wg * bfhi(u);
  }
  float inv = 1.0f / den;
  float v0 = a0 * inv + bias[2 * lane];
  float v1 = a1 * inv + bias[2 * lane + 1];
  outp[(size_t)wid * 64 + lane] = ((u32)f2bf(v1) << 16) | (u32)f2bf(v0);
}

// ---------------- GraphNorm stats from bf16 h: E[h], E[h^2] ----------------
__global__ void k_gn_stats(const u32* __restrict__ h32, float* __restrict__ acc) {
  __shared__ float r0[256], r1[256], r2[256], r3[256];
  int tid = threadIdx.x;
  int p = tid & 63, rg = tid >> 6;   // feature-pair, row group 0..3
  float s0 = 0.0f, q0 = 0.0f, s1 = 0.0f, q1 = 0.0f;
  for (int r = blockIdx.x * 4 + rg; r < NN; r += gridDim.x * 4) {
    u32 u = h32[(size_t)r * 64 + p];
    float a = bflo(u), b = bfhi(u);
    s0 += a; q0 += a * a; s1 += b; q1 += b * b;
  }
  r0[tid] = s0; r1[tid] = q0; r2[tid] = s1; r3[tid] = q1;
  __syncthreads();
  if (tid < 64) {
    float t0 = r0[tid] + r0[tid + 64] + r0[tid + 128] + r0[tid + 192];
    float t1 = r1[tid] + r1[tid + 64] + r1[tid + 128] + r1[tid + 192];
    float t2 = r2[tid] + r2[tid + 64] + r2[tid + 128] + r2[tid + 192];
    float t3 = r3[tid] + r3[tid + 64] + r3[tid + 128] + r3[tid + 192];
    atomicAdd(&acc[2 * tid], t0);
    atomicAdd(&acc[DD + 2 * tid], t1);
    atomicAdd(&acc[2 * tid + 1], t2);
    atomicAdd(&acc[DD + 2 * tid + 1], t3);
  }
}

// ---------------- GraphNorm apply + ReLU, bf16 -> bf16 ----------------
__global__ void k_gn_apply(const u32* __restrict__ hin, const float* __restrict__ acc,
                           const float* __restrict__ ms, const float* __restrict__ w, const float* __restrict__ b,
                           u32* __restrict__ hout) {
  const float invN = 1.0f / NN;
  for (size_t i = (size_t)blockIdx.x * 256 + threadIdx.x; i < (size_t)NN * 64; i += (size_t)gridDim.x * 256) {
    int p = (int)(i & 63);
    int f0 = 2 * p, f1 = f0 + 1;
    u32 u = hin[i];
    float mu0 = acc[f0] * invN, qm0 = acc[DD + f0] * invN;
    float sub0 = mu0 * ms[f0];
    float var0 = qm0 - 2.0f * sub0 * mu0 + sub0 * sub0;
    float v0 = (bflo(u) - sub0) * rsqrtf(var0 + 1e-5f) * w[f0] + b[f0];
    float mu1 = acc[f1] * invN, qm1 = acc[DD + f1] * invN;
    float sub1 = mu1 * ms[f1];
    float var1 = qm1 - 2.0f * sub1 * mu1 + sub1 * sub1;
    float v1 = (bfhi(u) - sub1) * rsqrtf(var1 + 1e-5f) * w[f1] + b[f1];
    v0 = fmaxf(v0, 0.0f); v1 = fmaxf(v1, 0.0f);
    hout[i] = ((u32)f2bf(v1) << 16) | (u32)f2bf(v0);
  }
}

// ---------------- BatchNorm (batch stats) + ReLU + bf16 ----------------
__global__ void k_bn(const float* __restrict__ z, const float* __restrict__ w, const float* __restrict__ b,
                     u16* __restrict__ zb) {
  int c = blockIdx.x;
  int lane = threadIdx.x;
  float s = 0.0f, s2 = 0.0f;
  for (int r = lane; r < BB; r += 64) {
    float v = z[(size_t)r * D3 + c];
    s += v; s2 += v * v;
  }
  #pragma unroll
  for (int o = 32; o; o >>= 1) { s += __shfl_xor(s, o, 64); s2 += __shfl_xor(s2, o, 64); }
  float mu = s * (1.0f / BB);
  float var = s2 * (1.0f / BB) - mu * mu;
  float sc = rsqrtf(var + 1e-5f) * w[c];
  float sb = b[c];
  for (int r = lane; r < BB; r += 64) {
    float v = (z[(size_t)r * D3 + c] - mu) * sc + sb;
    zb[(size_t)r * D3 + c] = f2bf(fmaxf(v, 0.0f));
  }
}

// ---------------- fused LSE-reduce + subtract: one block per row ----------------
// bf16-z path: out = bf16(z) - L
__global__ __launch_bounds__(256) void k_lsesub_bf(const float* __restrict__ pm, const float* __restrict__ ps,
                                                   const u16* __restrict__ zb, float* __restrict__ out) {
  __shared__ float sm[256], ss[256];
  int row = blockIdx.x, tid = threadIdx.x;
  float M = -3.0e38f, S = 0.0f;
  for (int b = tid; b < NTL2; b += 256) {
    float m = pm[(size_t)b * BB + row];
    float s = ps[(size_t)b * BB + row];
    float Mn = fmaxf(M, m);
    S = S * __expf(M - Mn) + s * __expf(m - Mn);
    M = Mn;
  }
  sm[tid] = M; ss[tid] = S;
  __syncthreads();
  for (int st = 128; st > 0; st >>= 1) {
    if (tid < st) {
      float m2 = sm[tid + st], s2 = ss[tid + st];
      float Mn = fmaxf(sm[tid], m2);
      ss[tid] = ss[tid] * __expf(sm[tid] - Mn) + s2 * __expf(m2 - Mn);
      sm[tid] = Mn;
    }
    __syncthreads();
  }
  float L = sm[0] + logf(ss[0]);
  const uint4* zr = (const uint4*)(zb + (size_t)row * NN);   // row = 6250 uint4 (16B-aligned: 100000%16==0)
  float4* orow = (float4*)(out + (size_t)row * NN);
  for (int i = tid; i < NN / 8; i += 256) {
    uint4 vv = zr[i];
    float4 o0, o1;
    o0.x = bflo(vv.x) - L; o0.y = bfhi(vv.x) - L;
    o0.z = bflo(vv.y) - L; o0.w = bfhi(vv.y) - L;
    o1.x = bflo(vv.z) - L; o1.y = bfhi(vv.z) - L;
    o1.z = bflo(vv.w) - L; o1.w = bfhi(vv.w) - L;
    orow[2 * i]     = o0;
    orow[2 * i + 1] = o1;
  }
}

// fp32 fallback: z -= L in place
__global__ __launch_bounds__(256) void k_lsesub_f32(const float* __restrict__ pm, const float* __restrict__ ps,
                                                    float* __restrict__ z) {
  __shared__ float sm[256], ss[256];
  int row = blockIdx.x, tid = threadIdx.x;
  float M = -3.0e38f, S = 0.0f;
  for (int b = tid; b < NTL2; b += 256) {
    float m = pm[(size_t)b * BB + row];
    float s = ps[(size_t)b * BB + row];
    float Mn = fmaxf(M, m);
    S = S * __expf(M - Mn) + s * __expf(m - Mn);
    M = Mn;
  }
  sm[tid] = M; ss[tid] = S;
  __syncthreads();
  for (int st = 128; st > 0; st >>= 1) {
    if (tid < st) {
      float m2 = sm[tid + st], s2 = ss[tid + st];
      float Mn = fmaxf(sm[tid], m2);
      ss[tid] = ss[tid] * __expf(sm[tid] - Mn) + s2 * __expf(m2 - Mn);
      sm[tid] = Mn;
    }
    __syncthreads();
  }
  float L = sm[0] + logf(ss[0]);
  float4* zr = (float4*)(z + (size_t)row * NN);
  for (int i = tid; i < NN / 4; i += 256) {
    float4 v = zr[i];
    v.x -= L; v.y -= L; v.z -= L; v.w -= L;
    zr[i] = v;
  }
}

// ---------------- launcher ----------------
extern "C" void kernel_launch(void* const* d_in, const int* in_sizes, int n_in,
                              void* d_out, int out_size, void* d_ws, size_t ws_size,
                              hipStream_t stream) {
  const int*   x     = (const int*)d_in[0];
  const int*   eidx  = (const int*)d_in[1];
  const float* emb   = (const float*)d_in[2];
  const float* W1    = (const float*)d_in[3];
  const float* as1   = (const float*)d_in[4];
  const float* ad1   = (const float*)d_in[5];
  const float* b1    = (const float*)d_in[6];
  const float* gn1w  = (const float*)d_in[7];
  const float* gn1b  = (const float*)d_in[8];
  const float* gn1ms = (const float*)d_in[9];
  const float* W2    = (const float*)d_in[10];
  const float* as2   = (const float*)d_in[11];
  const float* ad2   = (const float*)d_in[12];
  const float* b2    = (const float*)d_in[13];
  const float* gn2w  = (const float*)d_in[14];
  const float* gn2b  = (const float*)d_in[15];
  const float* gn2ms = (const float*)d_in[16];
  const float* l1W   = (const float*)d_in[17];
  const float* l1b   = (const float*)d_in[18];
  const float* bnw   = (const float*)d_in[19];
  const float* bnb   = (const float*)d_in[20];
  const float* l2W   = (const float*)d_in[21];
  const float* l2b   = (const float*)d_in[22];
  float* out = (float*)d_out;
  char*  dob = (char*)d_out;

  // bf16 12.8 MB regions in d_out (all dead before the final output write):
  // R0: embb -> agg1 out -> agg2 out ; R1: L1 gemm out -> L2 gemm out ; R2: apply1 out -> apply2 out
  u16* R0 = (u16*)(dob);
  u16* R1 = (u16*)(dob + (16u << 20));
  u16* R2 = (u16*)(dob + (32u << 20));

  char* wsb = (char*)d_ws;
  size_t o = 0;
  auto alloc = [&](size_t bytes) -> void* {
    void* p = wsb + o;
    o = (o + bytes + 255) & ~(size_t)255;
    return p;
  };
  int*   ssrc = (int*)alloc((size_t)EP * 4);
  int*   cnt  = (int*)alloc((size_t)NN * 4);
  int*   offs = (int*)alloc((size_t)NN * 4);
  int*   cur  = (int*)alloc((size_t)NN * 4);
  float* as_  = (float*)alloc((size_t)NN * 4);
  float* ad_  = (float*)alloc((size_t)NN * 4);
  int*   bsum = (int*)alloc(64 * 4);
  float* gnacc= (float*)alloc(2 * DD * 4);
  u16*   W1b  = (u16*)alloc((size_t)DD * DD * 2);
  u16*   W2b  = (u16*)alloc((size_t)DD * DD * 2);
  u16*   l1Wb = (u16*)alloc((size_t)D3 * D3 * 2);
  float* z2   = (float*)alloc((size_t)BB * D3 * 4);
  u16*   zbf  = (u16*)alloc((size_t)BB * D3 * 2);
  u16*   l2Wb = (u16*)alloc((size_t)NN * D3 * 2);      // 38.4 MB bf16 copy of l2W
  float* pm   = (float*)alloc((size_t)NTL2 * BB * 4);  // softmax partial max [391][1024]
  float* ps   = (float*)alloc((size_t)NTL2 * BB * 4);  // softmax partial sumexp
  // optional bf16 z buffer (102.4 MB) -- only if the workspace is big enough
  u16* zb2 = nullptr;
  if (ws_size >= o + (size_t)BB * NN * 2 + 256) zb2 = (u16*)alloc((size_t)BB * NN * 2);

  // ---- all weight/embedding converts in one launch ----
  {
    int nE = NN * DD / 4, nL2 = NN * D3 / 4, nW = DD * DD / 4, nL1 = D3 * D3 / 4;
    int tot = nE + nL2 + 2 * nW + nL1;
    k_f2bf5<<<(tot + 255) / 256, 256, 0, stream>>>(emb, R0, nE, l2W, l2Wb, nL2,
                                                   W1, W1b, nW, W2, W2b, nW, l1W, l1Wb, nL1);
  }

  // ---- CSR by dst ----
  hipMemsetAsync(cnt, 0, (size_t)NN * 4, stream);
  k_count  <<<(EP + 255) / 256, 256, 0, stream>>>(eidx, cnt);
  k_scan1  <<<49, 1024, 0, stream>>>(cnt, offs, bsum);
  k_scan23 <<<(NN + 255) / 256, 256, 0, stream>>>(offs, bsum, cur);
  k_scatter<<<(EP + 255) / 256, 256, 0, stream>>>(eidx, cur, ssrc);

  // ---- GAT layer 1 (GEMM + fused attention coefficients) ----
  gemm_tile<true, true, false><<<dim3(1, 391), 256, 0, stream>>>(
      R0, W1b, nullptr, R1, NN, DD, DD, as_, ad_, as1, ad1, nullptr);
  k_agg<<<(NN + 3) / 4, 256, 0, stream>>>(R1, as_, ad_, offs, cnt, ssrc, b1, (u32*)R0);
  hipMemsetAsync(gnacc, 0, 2 * DD * 4, stream);
  k_gn_stats<<<256, 256, 0, stream>>>((const u32*)R0, gnacc);
  k_gn_apply<<<4096, 256, 0, stream>>>((const u32*)R0, gnacc, gn1ms, gn1w, gn1b, (u32*)R2);

  // ---- GAT layer 2 ----
  gemm_tile<true, true, false><<<dim3(1, 391), 256, 0, stream>>>(
      R2, W2b, nullptr, R1, NN, DD, DD, as_, ad_, as2, ad2, nullptr);
  k_agg<<<(NN + 3) / 4, 256, 0, stream>>>(R1, as_, ad_, offs, cnt, ssrc, b2, (u32*)R0);
  hipMemsetAsync(gnacc, 0, 2 * DD * 4, stream);
  k_gn_stats<<<256, 256, 0, stream>>>((const u32*)R0, gnacc);
  k_gn_apply<<<4096, 256, 0, stream>>>((const u32*)R0, gnacc, gn2ms, gn2w, gn2b, (u32*)R2);

  // ---- head ----
  // lin1: A gathered directly from R2 (bf16 h) via x
  gemm_tile<false, false, true><<<dim3(3, 8), 256, 0, stream>>>(
      R2, l1Wb, l1b, z2, BB, D3, D3, nullptr, nullptr, nullptr, nullptr, x);
  k_bn<<<D3, 64, 0, stream>>>(z2, bnw, bnb, zbf);
  // lin2: 256x128-tile GEMM + fused per-tile softmax partials
  if (zb2) {
    gemm_lin2<true><<<dim3(NTL2, 4), 256, 0, stream>>>(zbf, l2Wb, l2b, zb2, pm, ps);
    k_lsesub_bf<<<BB, 256, 0, stream>>>(pm, ps, zb2, out);
  } else {
    gemm_lin2<false><<<dim3(NTL2, 4), 256, 0, stream>>>(zbf, l2Wb, l2b, out, pm, ps);
    k_lsesub_f32<<<BB, 256, 0, stream>>>(pm, ps, out);
  }
}

// Round 5
// 767.094 us; speedup vs baseline: 1.0880x; 1.0880x over previous
//
#include <hip/hip_runtime.h>
#include <cstdint>
#include <cstddef>

#define NN 50000
#define EE 800000
#define EP 850000   // EE + NN self-loops
#define DD 128
#define BB 1024
#define D3 384
#define NTL2 391    // ceil(NN/128) column tiles of lin2
#define NEG_SLOPE 0.2f

typedef __attribute__((ext_vector_type(8))) short short8;
typedef __attribute__((ext_vector_type(4))) float f32x4;
typedef unsigned short u16;
typedef unsigned int u32;

__device__ __forceinline__ u16 f2bf(float f) {
  u32 u = __float_as_uint(f);
  u += 0x7fffu + ((u >> 16) & 1u);
  return (u16)(u >> 16);
}
__device__ __forceinline__ float bflo(u32 u) { return __uint_as_float(u << 16); }
__device__ __forceinline__ float bfhi(u32 u) { return __uint_as_float(u & 0xffff0000u); }

// async global->LDS 16B: per-lane global addr, wave-uniform LDS base (+lane*16 by HW)
__device__ __forceinline__ void gl2lds16(const u16* g, u16* lds_base_uniform) {
  __builtin_amdgcn_global_load_lds((const __attribute__((address_space(1))) u32*)g,
                                   (__attribute__((address_space(3))) u32*)lds_base_uniform,
                                   16, 0, 0);
}

// ---------------- fused fp32 -> bf16 converts (5 regions, 1 launch) ----------------
__global__ void k_f2bf5(const float* __restrict__ s0, u16* __restrict__ d0, int n0,
                        const float* __restrict__ s1, u16* __restrict__ d1, int n1,
                        const float* __restrict__ s2, u16* __restrict__ d2, int n2,
                        const float* __restrict__ s3, u16* __restrict__ d3, int n3,
                        const float* __restrict__ s4, u16* __restrict__ d4, int n4) {
  int i = blockIdx.x * 256 + threadIdx.x;
  const float* s; u16* d; int j;
  int c0 = n0, c1 = c0 + n1, c2 = c1 + n2, c3 = c2 + n3, c4 = c3 + n4;
  if      (i < c0) { s = s0; d = d0; j = i; }
  else if (i < c1) { s = s1; d = d1; j = i - c0; }
  else if (i < c2) { s = s2; d = d2; j = i - c1; }
  else if (i < c3) { s = s3; d = d3; j = i - c2; }
  else if (i < c4) { s = s4; d = d4; j = i - c3; }
  else return;
  float4 v = ((const float4*)s)[j];
  ushort4 o;
  o.x = f2bf(v.x); o.y = f2bf(v.y); o.z = f2bf(v.z); o.w = f2bf(v.w);
  ((ushort4*)d)[j] = o;
}

// ---------------- CSR build (counting sort by dst) ----------------
__global__ void k_count(const int* __restrict__ eidx, int* __restrict__ cnt) {
  int e = blockIdx.x * 256 + threadIdx.x;
  if (e >= EP) return;
  int d = (e < EE) ? eidx[EE + e] : (e - EE);
  atomicAdd(&cnt[d], 1);
}

// shfl-based block scan: 16 waves x 64-lane shfl scan, 2 barriers total
__global__ void k_scan1(const int* __restrict__ cnt, int* __restrict__ offs, int* __restrict__ bsum) {
  __shared__ int wsum[16], wexc[16];
  int tid = threadIdx.x;
  int wv = tid >> 6, lane = tid & 63;
  int i = blockIdx.x * 1024 + tid;
  int v = (i < NN) ? cnt[i] : 0;
  int s = v;
  #pragma unroll
  for (int off = 1; off < 64; off <<= 1) {
    int t = __shfl_up(s, off, 64);
    if (lane >= off) s += t;
  }
  if (lane == 63) wsum[wv] = s;
  __syncthreads();
  if (tid < 16) {
    int u = wsum[tid];
    int e = u;
    #pragma unroll
    for (int off = 1; off < 16; off <<= 1) {
      int t = __shfl_up(e, off, 64);
      if (tid >= off) e += t;
    }
    wexc[tid] = e - u;   // exclusive wave offset
  }
  __syncthreads();
  int inc = s + wexc[wv];
  if (i < NN) offs[i] = inc - v;   // exclusive
  if (tid == 1023) bsum[blockIdx.x] = inc;
}

// scan of 49 block sums (done redundantly per block, wave 0) + apply, fused
__global__ void k_scan23(int* __restrict__ offs, const int* __restrict__ bsum, int* __restrict__ cur) {
  __shared__ int bso_s[64];
  int tid = threadIdx.x;
  if (tid < 64) {
    int v = (tid < 49) ? bsum[tid] : 0;
    int s = v;
    #pragma unroll
    for (int off = 1; off < 64; off <<= 1) {
      int t = __shfl_up(s, off, 64);
      if (tid >= off) s += t;
    }
    bso_s[tid] = s - v;
  }
  __syncthreads();
  int i = blockIdx.x * 256 + tid;
  if (i >= NN) return;
  int o = offs[i] + bso_s[i >> 10];
  offs[i] = o;
  cur[i] = o;
}

__global__ void k_scatter(const int* __restrict__ eidx, int* __restrict__ cur, int* __restrict__ ssrc) {
  int e = blockIdx.x * 256 + threadIdx.x;
  if (e >= EP) return;
  int s, d;
  if (e < EE) { s = eidx[e]; d = eidx[EE + e]; } else { s = e - EE; d = s; }
  int p = atomicAdd(&cur[d], 1);
  ssrc[p] = s;
}

// ---------------- m97-style tiled MFMA GEMM (128x128 tile, 96 VGPR, 32 KB LDS) ----------------
// C[M,N] = A[M,K] @ B[N,K]^T (+bias). A,B bf16 via global_load_lds.
// STATS : emit per-(col-tile, row) softmax partials (max, sumexp) -> pm/ps.
// SWZ   : XCD-chunked block swizzle (requires nwg%8==0, gridDim.y==8) for B-panel L2 reuse.
// ATT   : epilogue computes as_ = h@attS, ad_ = h@attD per row -> pm/ps (gridDim.x==1, N==128).
// GATHER: A row r is xmap-indirected: A[xmap[r*3 + kt/128]*DD + (kt&127)+...] (lin1 concat-gather).
template<bool OUT_BF16, bool STATS, bool SWZ, bool ATT, bool GATHER>
__global__ __launch_bounds__(256) void gemm_tile(const u16* __restrict__ A, const u16* __restrict__ B,
                                                 const float* __restrict__ bias, void* __restrict__ Cv,
                                                 int M, int N, int K,
                                                 float* __restrict__ pm, float* __restrict__ ps,
                                                 const float* __restrict__ attS, const float* __restrict__ attD,
                                                 const int* __restrict__ xmap) {
  __shared__ u16 As[16 * 512];   // 16 KB: [128 rows][64 k] bf16, swizzled
  __shared__ u16 Bs[16 * 512];
  int tid = threadIdx.x;
  int w = tid >> 6, lane = tid & 63;
  int l15 = lane & 15, q = lane >> 4;

  int bx = blockIdx.x, by = blockIdx.y;
  if constexpr (SWZ) {
    // id%8 ~ XCD (round-robin model). Each XCD gets a contiguous chunk of s-space;
    // decoding (by = s&7, bx = s>>3) iterates row tiles fastest -> B panel L2-resident.
    int id = by * gridDim.x + bx;
    int chunk = (gridDim.x * gridDim.y) >> 3;
    int s = (id & 7) * chunk + (id >> 3);
    by = s & 7;          // gridDim.y == 8
    bx = s >> 3;
  }
  int n0 = bx * 128, m0 = by * 128;
  int mh = w & 1, nh = w >> 1;

  // staging lane geometry
  int lr = lane >> 3;                 // row-in-8
  int cg = (lane & 7) ^ lr;           // global chunk to fetch for this lane's slot

  f32x4 acc[4][4] = {};

  for (int kt = 0; kt < K; kt += 64) {
    // ---- stage A ----
    #pragma unroll
    for (int i = 0; i < 4; i++) {
      int inst = (w << 2) | i;
      int row = inst * 8 + lr;
      int grow = m0 + row; if (grow > M - 1) grow = M - 1;
      const u16* src;
      if constexpr (GATHER) {
        int node = xmap[grow * 3 + (kt >> 7)];
        src = A + (size_t)node * DD + (kt & 127) + cg * 8;
      } else {
        src = A + (size_t)grow * K + kt + cg * 8;
      }
      gl2lds16(src, &As[inst * 512]);
    }
    // ---- stage B ----
    #pragma unroll
    for (int i = 0; i < 4; i++) {
      int inst = (w << 2) | i;
      int row = inst * 8 + lr;
      int gn = n0 + row; if (gn > N - 1) gn = N - 1;
      gl2lds16(B + (size_t)gn * K + kt + cg * 8, &Bs[inst * 512]);
    }
    __builtin_amdgcn_s_waitcnt(0x0f70);  // vmcnt(0) for global_load_lds
    __syncthreads();

    // ---- compute: 2 kk-steps x 16 MFMA ----
    #pragma unroll
    for (int kk = 0; kk < 2; kk++) {
      short8 a[4], b[4];
      int cbase = kk * 4 + q;
      int csw = cbase ^ (l15 & 7);
      #pragma unroll
      for (int mi = 0; mi < 4; mi++) {
        int row = (mh * 4 + mi) * 16 + l15;
        a[mi] = *(const short8*)(&As[row * 64 + csw * 8]);
      }
      #pragma unroll
      for (int nt = 0; nt < 4; nt++) {
        int row = (nh * 4 + nt) * 16 + l15;
        b[nt] = *(const short8*)(&Bs[row * 64 + csw * 8]);
      }
      #pragma unroll
      for (int mi = 0; mi < 4; mi++)
        #pragma unroll
        for (int nt = 0; nt < 4; nt++)
          acc[mi][nt] = __builtin_amdgcn_mfma_f32_16x16x32_bf16(a[mi], b[nt], acc[mi][nt], 0, 0, 0);
    }
    __syncthreads();   // WAR before next stage; also frees LDS for epilogue reuse
  }

  // ---- epilogue ----
  float bsv[4], asv[4], adv[4];
  #pragma unroll
  for (int nt = 0; nt < 4; nt++) {
    int col = n0 + nh * 64 + nt * 16 + l15;
    bsv[nt] = (bias != nullptr && col < N) ? bias[col] : 0.0f;
    if constexpr (ATT) { asv[nt] = attS[col]; adv[nt] = attD[col]; }
  }
  float* sredS = (float*)As;   // STATS: [0..255]=max,[256..511]=sumexp ; ATT: s-partials
  float* sredD = (float*)Bs;   // ATT: d-partials

  #pragma unroll
  for (int mi = 0; mi < 4; mi++) {
    #pragma unroll
    for (int r = 0; r < 4; r++) {
      int rw = m0 + mh * 64 + mi * 16 + q * 4 + r;
      float v[4];
      #pragma unroll
      for (int nt = 0; nt < 4; nt++) {
        int col = n0 + nh * 64 + nt * 16 + l15;
        v[nt] = acc[mi][nt][r] + bsv[nt];
        if (col < N && rw < M) {
          if constexpr (OUT_BF16) ((u16*)Cv)[(size_t)rw * N + col] = f2bf(v[nt]);
          else                    ((float*)Cv)[(size_t)rw * N + col] = v[nt];
        }
        if constexpr (STATS) { if (col >= N) v[nt] = -3.0e38f; }
      }
      if constexpr (STATS) {
        // per-row (max, sumexp) over this wave's 64 cols: reduce across the 16-lane l15 group
        float mx = fmaxf(fmaxf(v[0], v[1]), fmaxf(v[2], v[3]));
        #pragma unroll
        for (int o = 1; o <= 8; o <<= 1) mx = fmaxf(mx, __shfl_xor(mx, o, 64));
        float s = __expf(v[0] - mx) + __expf(v[1] - mx) + __expf(v[2] - mx) + __expf(v[3] - mx);
        #pragma unroll
        for (int o = 1; o <= 8; o <<= 1) s += __shfl_xor(s, o, 64);
        if (l15 == 0) {
          int ri = w * 64 + mi * 16 + q * 4 + r;
          sredS[ri] = mx;
          sredS[256 + ri] = s;
        }
      }
      if constexpr (ATT) {
        float psm = v[0] * asv[0] + v[1] * asv[1] + v[2] * asv[2] + v[3] * asv[3];
        float pdm = v[0] * adv[0] + v[1] * adv[1] + v[2] * adv[2] + v[3] * adv[3];
        #pragma unroll
        for (int o = 1; o <= 8; o <<= 1) { psm += __shfl_xor(psm, o, 64); pdm += __shfl_xor(pdm, o, 64); }
        if (l15 == 0) {
          int ri = w * 64 + mi * 16 + q * 4 + r;
          sredS[ri] = psm;
          sredD[ri] = pdm;
        }
      }
    }
  }
  if constexpr (STATS) {
    __syncthreads();
    int t = threadIdx.x;
    if (t < 128) {
      // rows 0..63 live in waves {0,2} (mh=0); rows 64..127 in waves {1,3}
      int half = t >> 6, rr = t & 63;
      float ma = sredS[half * 64 + rr],        mb = sredS[half * 64 + 128 + rr];
      float sa = sredS[256 + half * 64 + rr],  sb = sredS[256 + half * 64 + 128 + rr];
      float M2 = fmaxf(ma, mb);
      float S2 = sa * __expf(ma - M2) + sb * __expf(mb - M2);
      int grow = m0 + half * 64 + rr;
      pm[(size_t)bx * M + grow] = M2;
      ps[(size_t)bx * M + grow] = S2;
    }
  }
  if constexpr (ATT) {
    __syncthreads();
    int t = threadIdx.x;
    if (t < 128) {
      int half = t >> 6, rr = t & 63;
      int grow = m0 + half * 64 + rr;
      if (grow < M) {
        pm[grow] = sredS[half * 64 + rr] + sredS[half * 64 + 128 + rr];   // as_
        ps[grow] = sredD[half * 64 + rr] + sredD[half * 64 + 128 + rr];   // ad_
      }
    }
  }
}

// ---------------- GAT aggregation: one wave per dst node, SINGLE PASS, bf16 out ----------------
// Softmax is shift-invariant; |e| is small with these weight scales, so no max pass.
// den accumulates identically in every lane (w computed redundantly) -> no reduction.
__global__ void k_agg(const u16* __restrict__ hb, const float* __restrict__ as_, const float* __restrict__ ad_,
                      const int* __restrict__ offs, const int* __restrict__ cnt, const int* __restrict__ ssrc,
                      const float* __restrict__ bias, u32* __restrict__ outp) {
  int wid = (blockIdx.x * 256 + threadIdx.x) >> 6;
  int lane = threadIdx.x & 63;
  if (wid >= NN) return;
  int start = offs[wid], deg = cnt[wid];
  float add = ad_[wid];

  const u32* hp = (const u32*)hb;   // row stride 64 u32
  float a0 = 0.0f, a1 = 0.0f, den = 0.0f;
  int i = 0;
  for (; i + 4 <= deg; i += 4) {
    int s0 = ssrc[start + i + 0], s1 = ssrc[start + i + 1];
    int s2 = ssrc[start + i + 2], s3 = ssrc[start + i + 3];
    u32 u0 = hp[(size_t)s0 * 64 + lane];
    u32 u1 = hp[(size_t)s1 * 64 + lane];
    u32 u2 = hp[(size_t)s2 * 64 + lane];
    u32 u3 = hp[(size_t)s3 * 64 + lane];
    float e0 = as_[s0] + add, e1 = as_[s1] + add, e2 = as_[s2] + add, e3 = as_[s3] + add;
    e0 = (e0 >= 0.0f) ? e0 : NEG_SLOPE * e0;
    e1 = (e1 >= 0.0f) ? e1 : NEG_SLOPE * e1;
    e2 = (e2 >= 0.0f) ? e2 : NEG_SLOPE * e2;
    e3 = (e3 >= 0.0f) ? e3 : NEG_SLOPE * e3;
    float w0 = __expf(e0), w1 = __expf(e1), w2 = __expf(e2), w3 = __expf(e3);
    den += (w0 + w1) + (w2 + w3);
    a0 += w0 * bflo(u0) + w1 * bflo(u1) + w2 * bflo(u2) + w3 * bflo(u3);
    a1 += w0 * bfhi(u0) + w1 * bfhi(u1) + w2 * bfhi(u2) + w3 * bfhi(u3);
  }
  for (; i < deg; i++) {
    int s = ssrc[start + i];
    u32 u = hp[(size_t)s * 64 + lane];
    float e = as_[s] + add;
    e = (e >= 0.0f) ? e : NEG_SLOPE * e;
    float wg = __expf(e);
    den += wg;
    a0 += wg * bflo(u);
    a1 += wg * bfhi(u);
  }
  float inv = 1.0f / den;
  float v0 = a0 * inv + bias[2 * lane];
  float v1 = a1 * inv + bias[2 * lane + 1];
  outp[(size_t)wid * 64 + lane] = ((u32)f2bf(v1) << 16) | (u32)f2bf(v0);
}

// ---------------- GraphNorm stats from bf16 h: E[h], E[h^2] ----------------
__global__ void k_gn_stats(const u32* __restrict__ h32, float* __restrict__ acc) {
  __shared__ float r0[256], r1[256], r2[256], r3[256];
  int tid = threadIdx.x;
  int p = tid & 63, rg = tid >> 6;   // feature-pair, row group 0..3
  float s0 = 0.0f, q0 = 0.0f, s1 = 0.0f, q1 = 0.0f;
  for (int r = blockIdx.x * 4 + rg; r < NN; r += gridDim.x * 4) {
    u32 u = h32[(size_t)r * 64 + p];
    float a = bflo(u), b = bfhi(u);
    s0 += a; q0 += a * a; s1 += b; q1 += b * b;
  }
  r0[tid] = s0; r1[tid] = q0; r2[tid] = s1; r3[tid] = q1;
  __syncthreads();
  if (tid < 64) {
    float t0 = r0[tid] + r0[tid + 64] + r0[tid + 128] + r0[tid + 192];
    float t1 = r1[tid] + r1[tid + 64] + r1[tid + 128] + r1[tid + 192];
    float t2 = r2[tid] + r2[tid + 64] + r2[tid + 128] + r2[tid + 192];
    float t3 = r3[tid] + r3[tid + 64] + r3[tid + 128] + r3[tid + 192];
    atomicAdd(&acc[2 * tid], t0);
    atomicAdd(&acc[DD + 2 * tid], t1);
    atomicAdd(&acc[2 * tid + 1], t2);
    atomicAdd(&acc[DD + 2 * tid + 1], t3);
  }
}

// ---------------- GraphNorm apply + ReLU, bf16 -> bf16 ----------------
__global__ void k_gn_apply(const u32* __restrict__ hin, const float* __restrict__ acc,
                           const float* __restrict__ ms, const float* __restrict__ w, const float* __restrict__ b,
                           u32* __restrict__ hout) {
  const float invN = 1.0f / NN;
  for (size_t i = (size_t)blockIdx.x * 256 + threadIdx.x; i < (size_t)NN * 64; i += (size_t)gridDim.x * 256) {
    int p = (int)(i & 63);
    int f0 = 2 * p, f1 = f0 + 1;
    u32 u = hin[i];
    float mu0 = acc[f0] * invN, qm0 = acc[DD + f0] * invN;
    float sub0 = mu0 * ms[f0];
    float var0 = qm0 - 2.0f * sub0 * mu0 + sub0 * sub0;
    float v0 = (bflo(u) - sub0) * rsqrtf(var0 + 1e-5f) * w[f0] + b[f0];
    float mu1 = acc[f1] * invN, qm1 = acc[DD + f1] * invN;
    float sub1 = mu1 * ms[f1];
    float var1 = qm1 - 2.0f * sub1 * mu1 + sub1 * sub1;
    float v1 = (bfhi(u) - sub1) * rsqrtf(var1 + 1e-5f) * w[f1] + b[f1];
    v0 = fmaxf(v0, 0.0f); v1 = fmaxf(v1, 0.0f);
    hout[i] = ((u32)f2bf(v1) << 16) | (u32)f2bf(v0);
  }
}

// ---------------- BatchNorm (batch stats) + ReLU + bf16 ----------------
__global__ void k_bn(const float* __restrict__ z, const float* __restrict__ w, const float* __restrict__ b,
                     u16* __restrict__ zb) {
  int c = blockIdx.x;
  int lane = threadIdx.x;
  float s = 0.0f, s2 = 0.0f;
  for (int r = lane; r < BB; r += 64) {
    float v = z[(size_t)r * D3 + c];
    s += v; s2 += v * v;
  }
  #pragma unroll
  for (int o = 32; o; o >>= 1) { s += __shfl_xor(s, o, 64); s2 += __shfl_xor(s2, o, 64); }
  float mu = s * (1.0f / BB);
  float var = s2 * (1.0f / BB) - mu * mu;
  float sc = rsqrtf(var + 1e-5f) * w[c];
  float sb = b[c];
  for (int r = lane; r < BB; r += 64) {
    float v = (z[(size_t)r * D3 + c] - mu) * sc + sb;
    zb[(size_t)r * D3 + c] = f2bf(fmaxf(v, 0.0f));
  }
}

// ---------------- fused LSE-reduce + subtract: one block per row ----------------
// bf16-z path: out = bf16(z) - L
__global__ __launch_bounds__(256) void k_lsesub_bf(const float* __restrict__ pm, const float* __restrict__ ps,
                                                   const u16* __restrict__ zb, float* __restrict__ out) {
  __shared__ float sm[256], ss[256];
  int row = blockIdx.x, tid = threadIdx.x;
  float M = -3.0e38f, S = 0.0f;
  for (int b = tid; b < NTL2; b += 256) {
    float m = pm[(size_t)b * BB + row];
    float s = ps[(size_t)b * BB + row];
    float Mn = fmaxf(M, m);
    S = S * __expf(M - Mn) + s * __expf(m - Mn);
    M = Mn;
  }
  sm[tid] = M; ss[tid] = S;
  __syncthreads();
  for (int st = 128; st > 0; st >>= 1) {
    if (tid < st) {
      float m2 = sm[tid + st], s2 = ss[tid + st];
      float Mn = fmaxf(sm[tid], m2);
      ss[tid] = ss[tid] * __expf(sm[tid] - Mn) + s2 * __expf(m2 - Mn);
      sm[tid] = Mn;
    }
    __syncthreads();
  }
  float L = sm[0] + logf(ss[0]);
  const uint4* zr = (const uint4*)(zb + (size_t)row * NN);   // row = 6250 uint4 (16B-aligned: 100000%16==0)
  float4* orow = (float4*)(out + (size_t)row * NN);
  for (int i = tid; i < NN / 8; i += 256) {
    uint4 vv = zr[i];
    float4 o0, o1;
    o0.x = bflo(vv.x) - L; o0.y = bfhi(vv.x) - L;
    o0.z = bflo(vv.y) - L; o0.w = bfhi(vv.y) - L;
    o1.x = bflo(vv.z) - L; o1.y = bfhi(vv.z) - L;
    o1.z = bflo(vv.w) - L; o1.w = bfhi(vv.w) - L;
    orow[2 * i]     = o0;
    orow[2 * i + 1] = o1;
  }
}

// fp32 fallback: z -= L in place
__global__ __launch_bounds__(256) void k_lsesub_f32(const float* __restrict__ pm, const float* __restrict__ ps,
                                                    float* __restrict__ z) {
  __shared__ float sm[256], ss[256];
  int row = blockIdx.x, tid = threadIdx.x;
  float M = -3.0e38f, S = 0.0f;
  for (int b = tid; b < NTL2; b += 256) {
    float m = pm[(size_t)b * BB + row];
    float s = ps[(size_t)b * BB + row];
    float Mn = fmaxf(M, m);
    S = S * __expf(M - Mn) + s * __expf(m - Mn);
    M = Mn;
  }
  sm[tid] = M; ss[tid] = S;
  __syncthreads();
  for (int st = 128; st > 0; st >>= 1) {
    if (tid < st) {
      float m2 = sm[tid + st], s2 = ss[tid + st];
      float Mn = fmaxf(sm[tid], m2);
      ss[tid] = ss[tid] * __expf(sm[tid] - Mn) + s2 * __expf(m2 - Mn);
      sm[tid] = Mn;
    }
    __syncthreads();
  }
  float L = sm[0] + logf(ss[0]);
  float4* zr = (float4*)(z + (size_t)row * NN);
  for (int i = tid; i < NN / 4; i += 256) {
    float4 v = zr[i];
    v.x -= L; v.y -= L; v.z -= L; v.w -= L;
    zr[i] = v;
  }
}

// ---------------- launcher ----------------
extern "C" void kernel_launch(void* const* d_in, const int* in_sizes, int n_in,
                              void* d_out, int out_size, void* d_ws, size_t ws_size,
                              hipStream_t stream) {
  const int*   x     = (const int*)d_in[0];
  const int*   eidx  = (const int*)d_in[1];
  const float* emb   = (const float*)d_in[2];
  const float* W1    = (const float*)d_in[3];
  const float* as1   = (const float*)d_in[4];
  const float* ad1   = (const float*)d_in[5];
  const float* b1    = (const float*)d_in[6];
  const float* gn1w  = (const float*)d_in[7];
  const float* gn1b  = (const float*)d_in[8];
  const float* gn1ms = (const float*)d_in[9];
  const float* W2    = (const float*)d_in[10];
  const float* as2   = (const float*)d_in[11];
  const float* ad2   = (const float*)d_in[12];
  const float* b2    = (const float*)d_in[13];
  const float* gn2w  = (const float*)d_in[14];
  const float* gn2b  = (const float*)d_in[15];
  const float* gn2ms = (const float*)d_in[16];
  const float* l1W   = (const float*)d_in[17];
  const float* l1b   = (const float*)d_in[18];
  const float* bnw   = (const float*)d_in[19];
  const float* bnb   = (const float*)d_in[20];
  const float* l2W   = (const float*)d_in[21];
  const float* l2b   = (const float*)d_in[22];
  float* out = (float*)d_out;
  char*  dob = (char*)d_out;

  // bf16 12.8 MB regions in d_out (all dead before the final output write):
  // R0: embb -> agg1 out -> agg2 out ; R1: L1 gemm out -> L2 gemm out ; R2: apply1 out -> apply2 out
  u16* R0 = (u16*)(dob);
  u16* R1 = (u16*)(dob + (16u << 20));
  u16* R2 = (u16*)(dob + (32u << 20));

  char* wsb = (char*)d_ws;
  size_t o = 0;
  auto alloc = [&](size_t bytes) -> void* {
    void* p = wsb + o;
    o = (o + bytes + 255) & ~(size_t)255;
    return p;
  };
  int*   ssrc = (int*)alloc((size_t)EP * 4);
  int*   cnt  = (int*)alloc((size_t)NN * 4);
  int*   offs = (int*)alloc((size_t)NN * 4);
  int*   cur  = (int*)alloc((size_t)NN * 4);
  float* as_  = (float*)alloc((size_t)NN * 4);
  float* ad_  = (float*)alloc((size_t)NN * 4);
  int*   bsum = (int*)alloc(64 * 4);
  float* gnacc= (float*)alloc(2 * DD * 4);
  u16*   W1b  = (u16*)alloc((size_t)DD * DD * 2);
  u16*   W2b  = (u16*)alloc((size_t)DD * DD * 2);
  u16*   l1Wb = (u16*)alloc((size_t)D3 * D3 * 2);
  float* z2   = (float*)alloc((size_t)BB * D3 * 4);
  u16*   zbf  = (u16*)alloc((size_t)BB * D3 * 2);
  u16*   l2Wb = (u16*)alloc((size_t)NN * D3 * 2);      // 38.4 MB bf16 copy of l2W
  float* pm   = (float*)alloc((size_t)NTL2 * BB * 4);  // softmax partial max [391][1024]
  float* ps   = (float*)alloc((size_t)NTL2 * BB * 4);  // softmax partial sumexp
  // optional bf16 z buffer (102.4 MB) -- only if the workspace is big enough
  u16* zb2 = nullptr;
  if (ws_size >= o + (size_t)BB * NN * 2 + 256) zb2 = (u16*)alloc((size_t)BB * NN * 2);

  // ---- all weight/embedding converts in one launch ----
  {
    int nE = NN * DD / 4, nL2 = NN * D3 / 4, nW = DD * DD / 4, nL1 = D3 * D3 / 4;
    int tot = nE + nL2 + 2 * nW + nL1;
    k_f2bf5<<<(tot + 255) / 256, 256, 0, stream>>>(emb, R0, nE, l2W, l2Wb, nL2,
                                                   W1, W1b, nW, W2, W2b, nW, l1W, l1Wb, nL1);
  }

  // ---- CSR by dst ----
  hipMemsetAsync(cnt, 0, (size_t)NN * 4, stream);
  k_count  <<<(EP + 255) / 256, 256, 0, stream>>>(eidx, cnt);
  k_scan1  <<<49, 1024, 0, stream>>>(cnt, offs, bsum);
  k_scan23 <<<(NN + 255) / 256, 256, 0, stream>>>(offs, bsum, cur);
  k_scatter<<<(EP + 255) / 256, 256, 0, stream>>>(eidx, cur, ssrc);

  // ---- GAT layer 1 (GEMM + fused attention coefficients) ----
  gemm_tile<true, false, false, true, false><<<dim3(1, 391), 256, 0, stream>>>(
      R0, W1b, nullptr, R1, NN, DD, DD, as_, ad_, as1, ad1, nullptr);
  k_agg<<<(NN + 3) / 4, 256, 0, stream>>>(R1, as_, ad_, offs, cnt, ssrc, b1, (u32*)R0);
  hipMemsetAsync(gnacc, 0, 2 * DD * 4, stream);
  k_gn_stats<<<256, 256, 0, stream>>>((const u32*)R0, gnacc);
  k_gn_apply<<<4096, 256, 0, stream>>>((const u32*)R0, gnacc, gn1ms, gn1w, gn1b, (u32*)R2);

  // ---- GAT layer 2 ----
  gemm_tile<true, false, false, true, false><<<dim3(1, 391), 256, 0, stream>>>(
      R2, W2b, nullptr, R1, NN, DD, DD, as_, ad_, as2, ad2, nullptr);
  k_agg<<<(NN + 3) / 4, 256, 0, stream>>>(R1, as_, ad_, offs, cnt, ssrc, b2, (u32*)R0);
  hipMemsetAsync(gnacc, 0, 2 * DD * 4, stream);
  k_gn_stats<<<256, 256, 0, stream>>>((const u32*)R0, gnacc);
  k_gn_apply<<<4096, 256, 0, stream>>>((const u32*)R0, gnacc, gn2ms, gn2w, gn2b, (u32*)R2);

  // ---- head ----
  // lin1: A gathered directly from R2 (bf16 h) via x
  gemm_tile<false, false, false, false, true><<<dim3(3, 8), 256, 0, stream>>>(
      R2, l1Wb, l1b, z2, BB, D3, D3, nullptr, nullptr, nullptr, nullptr, x);
  k_bn<<<D3, 64, 0, stream>>>(z2, bnw, bnb, zbf);
  // lin2: 128x128-tile GEMM (96 VGPR / 32 KB LDS -> 5 blocks/CU) + XCD swizzle + fused softmax partials
  if (zb2) {
    gemm_tile<true, true, true, false, false><<<dim3(NTL2, 8), 256, 0, stream>>>(
        zbf, l2Wb, l2b, zb2, BB, NN, D3, pm, ps, nullptr, nullptr, nullptr);
    k_lsesub_bf<<<BB, 256, 0, stream>>>(pm, ps, zb2, out);
  } else {
    gemm_tile<false, true, true, false, false><<<dim3(NTL2, 8), 256, 0, stream>>>(
        zbf, l2Wb, l2b, out, BB, NN, D3, pm, ps, nullptr, nullptr, nullptr);
    k_lsesub_f32<<<BB, 256, 0, stream>>>(pm, ps, out);
  }
}